// Round 3
// baseline (217.091 us; speedup 1.0000x reference)
//
#include <hip/hip_runtime.h>
#include <hip/hip_bf16.h>

// Problem constants
#define BB 4
#define LL 1024
#define DD 768
#define HH 12
#define HD 64
#define MREL 50
#define NBIAS 101   // 2*MREL+1
#define GK 768      // GEMM K (= DD)
#define STR 72      // attn K/V LDS stride in ushorts (144 B, b128-aligned)
#define BXS 68      // bias-idx LDS stride in ushorts (136 B, b64-aligned, 2-way banks)

#define NEG_INF (-__builtin_inff())

// Workspace layout (float offsets into d_ws)
#define QB_F   ((size_t)0)          // q bf16 [B,H,L,64] (pre-scaled 1/8 * log2e)
#define KB_F   ((size_t)1572864)    // k bf16 [B,H,L,64]
#define VTB_F  ((size_t)3145728)    // v^T bf16 [B,H,64,L]
#define XBF_F  ((size_t)4718592)    // query bf16; later aout bf16 [B,L,768]
#define WIBF_F ((size_t)6291456)    // in_proj_w bf16 [2304,768]
#define WOBF_F ((size_t)7176192)    // out_proj_w bf16 [768,768]
#define BIDX_F ((size_t)7471104)    // packed bias idx u16 [B,L(i),L(j)] = 8 MB
#define DT_F   ((size_t)9568256)    // dt[B]
// total ~9.57M floats = 38.3 MB

#define NQ4  (BB*LL*DD)       // 3145728
#define NWI4 (3*DD*DD)        // 1769472

typedef __attribute__((ext_vector_type(8)))  short bf16x8;
typedef __attribute__((ext_vector_type(4)))  float f32x4;
typedef __attribute__((ext_vector_type(16))) float f32x16;
typedef __attribute__((ext_vector_type(4)))  unsigned int u32x4;

__device__ __forceinline__ unsigned short f2bf(float f) {
    unsigned u = __float_as_uint(f);
    u += 0x7fffu + ((u >> 16) & 1u);   // RN-even (finite inputs)
    return (unsigned short)(u >> 16);
}

// async global->LDS, 16 bytes per lane (LDS dest = wave-uniform base + lane*16)
__device__ __forceinline__ void gload_lds16(const void* g, void* l) {
    __builtin_amdgcn_global_load_lds(
        (const __attribute__((address_space(1))) void*)g,
        (__attribute__((address_space(3))) void*)l, 16, 0, 0);
}

// ---------------------------------------------------------------------------
// prep_kernel: blocks 0..3 = per-batch dt (u64 composite-key rank-count
// nanmedian); blocks 4.. = fp32->bf16 cvt of query/in_proj_w/out_proj_w.
// ---------------------------------------------------------------------------
__global__ __launch_bounds__(256) void prep_kernel(
    const float* __restrict__ patch, float* __restrict__ dt,
    const float* __restrict__ q, const float* __restrict__ wi, const float* __restrict__ wo,
    unsigned short* __restrict__ qd_, unsigned short* __restrict__ wid,
    unsigned short* __restrict__ wod) {
    int tid = threadIdx.x;
    if (blockIdx.x >= 4) {
        int i = ((blockIdx.x - 4) * 256 + tid) * 4;
        const float* src; unsigned short* dst; int off;
        if (i < NQ4)              { src = q;  dst = qd_; off = i; }
        else if (i < NQ4 + NWI4)  { src = wi; dst = wid; off = i - NQ4; }
        else                      { src = wo; dst = wod; off = i - NQ4 - NWI4; }
        float4 v = *(const float4*)&src[off];
        ushort4 o;
        o.x = f2bf(v.x); o.y = f2bf(v.y); o.z = f2bf(v.z); o.w = f2bf(v.w);
        *(ushort4*)&dst[off] = o;
        return;
    }
    // ---- dt path (blocks 0..3) ----
    __shared__ __align__(16) float del[1024];
    __shared__ __align__(16) unsigned long long key64[1024];
    __shared__ int nvalid;
    __shared__ float acc;
    int b = blockIdx.x;
    if (tid == 0) { nvalid = 0; acc = 0.f; }
    __syncthreads();
    int cnt = 0;
#pragma unroll
    for (int r = 0; r < 4; ++r) {
        int i = tid + r * 256;
        float v = __builtin_nanf("");
        if (i < LL - 1) {
            v = patch[b * LL + i + 1] - patch[b * LL + i];
            if (v == v) ++cnt;
        }
        del[i] = v;
        unsigned bits = (v == v) ? __float_as_uint(v) : 0x7FC00000u;
        unsigned ordk = (bits & 0x80000000u) ? ~bits : (bits | 0x80000000u);
        key64[i] = ((unsigned long long)ordk << 10) | (unsigned)i;
    }
    atomicAdd(&nvalid, cnt);
    __syncthreads();
    int i0 = tid, i1 = tid + 256, i2 = tid + 512, i3 = tid + 768;
    float v0 = del[i0], v1 = del[i1], v2 = del[i2], v3 = del[i3];
    unsigned long long k0 = key64[i0], k1 = key64[i1], k2 = key64[i2], k3 = key64[i3];
    int c0 = 0, c1 = 0, c2 = 0, c3 = 0;
#define CMPK(kx) { unsigned long long _k = (kx); \
    c0 += (_k < k0) ? 1 : 0; c1 += (_k < k1) ? 1 : 0; \
    c2 += (_k < k2) ? 1 : 0; c3 += (_k < k3) ? 1 : 0; }
    for (int j = 0; j < 1024; j += 8) {
        ulonglong2 a = *(const ulonglong2*)&key64[j];
        ulonglong2 bq = *(const ulonglong2*)&key64[j + 2];
        ulonglong2 cq = *(const ulonglong2*)&key64[j + 4];
        ulonglong2 dq = *(const ulonglong2*)&key64[j + 6];
        CMPK(a.x); CMPK(a.y); CMPK(bq.x); CMPK(bq.y);
        CMPK(cq.x); CMPK(cq.y); CMPK(dq.x); CMPK(dq.y);
    }
#undef CMPK
    int n = nvalid;
#define FIN(vr, cr) if (vr == vr) { \
    if (n & 1) { if (cr == n / 2) atomicAdd(&acc, vr); } \
    else { if (cr == n / 2 - 1 || cr == n / 2) atomicAdd(&acc, 0.5f * vr); } }
    FIN(v0, c0); FIN(v1, c1); FIN(v2, c2); FIN(v3, c3);
#undef FIN
    __syncthreads();
    if (tid == 0) {
        float m = acc;
        float res = (n > 0 && m == m && fabsf(m) != __builtin_inff() && m > 0.f) ? m : 1.0f;
        dt[b] = res;
    }
}

// ---------------------------------------------------------------------------
// Packed bias indices (head-independent): bidx[b][i][j] = dp | (fr<<8)
// ---------------------------------------------------------------------------
__global__ __launch_bounds__(256) void bidx_kernel(const float* __restrict__ patch,
                                                   const float* __restrict__ dtb,
                                                   unsigned short* __restrict__ bidx) {
    int flat = (blockIdx.x * 256 + threadIdx.x) * 8;   // u16 index
    int b = flat >> 20;
    int rem = flat & 1048575;
    int i = rem >> 10;          // q row (slow)
    int j0 = rem & 1023;        // k row base (fast, 8 consecutive)
    float pi = patch[b * LL + i];
    float inv_dt = 1.0f / dtb[b];
    float4 pa = *(const float4*)&patch[b * LL + j0];
    float4 pb4 = *(const float4*)&patch[b * LL + j0 + 4];
    unsigned out[4];
#define MK(pj, jofs, dst, shift) { \
    int d = (j0 + jofs) - i; d = d < -MREL ? -MREL : (d > MREL ? MREL : d); \
    float rt = pi - (pj); \
    if (!(rt == rt) || rt < -(float)MREL || rt > (float)MREL) rt = 0.f; \
    float fr = fminf(fmaxf(rintf(rt * inv_dt), -(float)MREL), (float)MREL); \
    unsigned u = (unsigned)(d + MREL) | (((unsigned)((int)fr + MREL)) << 8); \
    dst |= (u << shift); }
    unsigned t;
    t = 0; MK(pa.x, 0, t, 0); MK(pa.y, 1, t, 16); out[0] = t;
    t = 0; MK(pa.z, 2, t, 0); MK(pa.w, 3, t, 16); out[1] = t;
    t = 0; MK(pb4.x, 4, t, 0); MK(pb4.y, 5, t, 16); out[2] = t;
    t = 0; MK(pb4.z, 6, t, 0); MK(pb4.w, 7, t, 16); out[3] = t;
#undef MK
    *(uint4*)&bidx[flat] = *(uint4*)&out[0];
}

// ---------------------------------------------------------------------------
// R12: m97-structure GEMM — 128x128 tile, BK=64, 4 waves (2x2), 4x4 frags of
// 16x16x32 per wave (32 MFMA per K-step), gload_lds16 staging, 2 barriers.
// Measured 874-912 TF class on gfx950 vs ~340-500 TF for 64-row tiles.
// SMEMN parametrizes the shared block so epilogues can reuse it for staging.
// ---------------------------------------------------------------------------
#define GEMM_MAIN(SMEMN)                                                       \
    __shared__ __align__(16) unsigned short smem_g[SMEMN];                     \
    unsigned short* As = smem_g;                                               \
    unsigned short* Bs = smem_g + 8192;                                        \
    int tid = threadIdx.x;                                                     \
    int m0 = blockIdx.x << 7, n0 = blockIdx.y << 7;                            \
    int lane = tid & 63, w = tid >> 6;                                         \
    int wr = w >> 1, wc = w & 1;                                               \
    int srow = tid >> 3, scol = (tid & 7) << 3;                                \
    const unsigned short* Ag = Ab + (size_t)(m0 + srow) * GK + scol;           \
    const unsigned short* Bg = Wb + (size_t)(n0 + srow) * GK + scol;           \
    f32x4 acc[4][4];                                                           \
    _Pragma("unroll") for (int i = 0; i < 4; ++i)                              \
        _Pragma("unroll") for (int j = 0; j < 4; ++j)                          \
            acc[i][j] = (f32x4){0.f, 0.f, 0.f, 0.f};                           \
    int qd_ = lane >> 4, rl = lane & 15;                                       \
    int rA = wr * 64 + rl, rB = wc * 64 + rl;                                  \
    for (int kc = 0; kc < GK; kc += 64) {                                      \
        __syncthreads();                                                       \
        _Pragma("unroll") for (int r = 0; r < 4; ++r)                          \
            gload_lds16(Ag + (size_t)(r * 32) * GK + kc, As + tid * 8 + r * 2048); \
        _Pragma("unroll") for (int r = 0; r < 4; ++r)                          \
            gload_lds16(Bg + (size_t)(r * 32) * GK + kc, Bs + tid * 8 + r * 2048); \
        __syncthreads();                                                       \
        _Pragma("unroll") for (int ks = 0; ks < 2; ++ks) {                     \
            bf16x8 af[4], bfr[4];                                              \
            _Pragma("unroll") for (int t = 0; t < 4; ++t)                      \
                af[t] = *(const bf16x8*)&As[(rA + t * 16) * 64 + ks * 32 + qd_ * 8]; \
            _Pragma("unroll") for (int t = 0; t < 4; ++t)                      \
                bfr[t] = *(const bf16x8*)&Bs[(rB + t * 16) * 64 + ks * 32 + qd_ * 8]; \
            _Pragma("unroll") for (int i = 0; i < 4; ++i)                      \
                _Pragma("unroll") for (int j = 0; j < 4; ++j)                  \
                    acc[i][j] = __builtin_amdgcn_mfma_f32_16x16x32_bf16(       \
                        af[i], bfr[j], acc[i][j], 0, 0, 0);                    \
        }                                                                      \
    }                                                                          \
    int colL = lane & 15, rq = lane >> 4;

// QKV projection. Tiles are 128 cols = exactly 2 heads; sections: y 0-5 = Q,
// 6-11 = K, 12-17 = V. All outputs staged in LDS ([128][136] u16, reusing
// As/Bs) then written as coalesced 128 B rows. V is staged TRANSPOSED.
__global__ __launch_bounds__(256) void qkv_gemm(
    const unsigned short* __restrict__ Ab, const unsigned short* __restrict__ Wb,
    const float* __restrict__ bias,
    unsigned short* __restrict__ qb, unsigned short* __restrict__ kb,
    unsigned short* __restrict__ vtb) {
    GEMM_MAIN(17408);   // max(2*8192 main, 128*136 staging)
    int sec = n0 / DD;
    int hh0 = (n0 - sec * DD) >> 6;     // first of the 2 heads in this tile
    unsigned short* Ts = smem_g;        // [128][136] u16
    __syncthreads();                    // all ds_reads of As/Bs done
    if (sec == 2) {
        // ---- V: transposed staging Ts[n_local][m_local] ----
#pragma unroll
        for (int j = 0; j < 4; ++j) {
            int col_t = wc * 64 + j * 16 + colL;
            float bn = bias[n0 + col_t];
#pragma unroll
            for (int i = 0; i < 4; ++i) {
                ushort4 o;
                o.x = f2bf(acc[i][j][0] + bn);
                o.y = f2bf(acc[i][j][1] + bn);
                o.z = f2bf(acc[i][j][2] + bn);
                o.w = f2bf(acc[i][j][3] + bn);
                *(ushort4*)&Ts[col_t * 136 + wr * 64 + i * 16 + rq * 4] = o;
            }
        }
        __syncthreads();
        int nl = tid >> 1, half = tid & 1;      // nl = dd-local 0..127
        int d768 = n0 + nl - 2 * DD;
        int hh = d768 >> 6, dd = d768 & 63;
        int b = m0 >> 10, l0 = (m0 & 1023) + half * 64;
        unsigned short* dst = vtb + (((size_t)b * HH + hh) * HD + dd) * LL + l0;
#pragma unroll
        for (int k = 0; k < 8; ++k)
            *(uint4*)&dst[k * 8] = *(const uint4*)&Ts[nl * 136 + half * 64 + k * 8];
    } else {
        // ---- Q/K: direct staging Ts[m_local][n_local] ----
        float scale = (sec == 0) ? 0.18033688011112042f : 1.0f;  // 0.125*log2(e)
#pragma unroll
        for (int j = 0; j < 4; ++j) {
            int col_t = wc * 64 + j * 16 + colL;
            float bn = bias[n0 + col_t];
#pragma unroll
            for (int i = 0; i < 4; ++i) {
                int row_t = wr * 64 + i * 16 + rq * 4;
#pragma unroll
                for (int r = 0; r < 4; ++r)
                    Ts[(row_t + r) * 136 + col_t] = f2bf((acc[i][j][r] + bn) * scale);
            }
        }
        __syncthreads();
        int ml = tid >> 1, half = tid & 1;      // ml = L-local 0..127
        int b = (m0 + ml) >> 10, l = (m0 + ml) & 1023;
        unsigned short* dst = (sec == 0 ? qb : kb)
                              + (((size_t)b * HH + hh0 + half) * LL + l) * HD;
#pragma unroll
        for (int k = 0; k < 8; ++k)
            *(uint4*)&dst[k * 8] = *(const uint4*)&Ts[ml * 136 + half * 64 + k * 8];
    }
}

// Out projection: aout bf16 [4096,768] x W^T -> fp32 out (direct fp32 stores:
// each quarter-wave row-segment is 64 B contiguous — acceptable).
__global__ __launch_bounds__(256) void out_gemm(
    const unsigned short* __restrict__ Ab, const unsigned short* __restrict__ Wb,
    const float* __restrict__ bias, float* __restrict__ C) {
    GEMM_MAIN(16384);
#pragma unroll
    for (int j = 0; j < 4; ++j) {
        int n = n0 + wc * 64 + j * 16 + colL;
        float bn = bias[n];
#pragma unroll
        for (int i = 0; i < 4; ++i) {
            int rowb = m0 + wr * 64 + i * 16 + rq * 4;
#pragma unroll
            for (int r = 0; r < 4; ++r)
                C[(size_t)(rowb + r) * DD + n] = acc[i][j][r] + bn;
        }
    }
}

// ---------------------------------------------------------------------------
// MFMA flash attention (R10 structure): in-register P via cvt_pk_bf16 +
// permlane32_swap; 2 barriers/iter; register prefetch of next tile.
// R12: setprio REVERTED (R11 A/B: +3 us regression — lockstep structure,
// T5 regime gate per m190).
// ---------------------------------------------------------------------------
__global__ __launch_bounds__(256) void attn_kernel(
    const unsigned short* __restrict__ QB, const unsigned short* __restrict__ KB,
    const unsigned short* __restrict__ VTB, const unsigned short* __restrict__ BIDX,
    const float* __restrict__ relb, unsigned short* __restrict__ aout) {
    __shared__ __align__(16) unsigned short smem[2 * 64 * STR + 64 * BXS];
    __shared__ float sb[NBIAS];
    __shared__ float psum_s[128];
    __shared__ float linv_s[64];
    unsigned short* Ks  = smem;                 // [64][STR]
    unsigned short* Vt  = smem + 64 * STR;      // [64][STR]
    unsigned short* Bxs = smem + 2 * 64 * STR;  // [64][BXS]
    float* fcomb = (float*)smem;                // 16 KB end-of-kernel combine (aliases Ks+Vt)

    int tid = threadIdx.x;
    int w = tid >> 6, lane = tid & 63, li = lane & 31, qd = lane >> 5;
    int jt = w & 1, it = w >> 1;
    int bh = blockIdx.x, b = bh / HH, h = bh - b * HH;
    int q0 = blockIdx.y << 6;
    if (tid < NBIAS) sb[tid] = relb[h * NBIAS + tid] * 1.44269504088896340736f;
    int i_loc = it * 32 + li;
    int i_abs = q0 + i_loc;
    bf16x8 kq[4];
    const unsigned short* qrow = QB + ((size_t)bh * LL + i_abs) * HD + qd * 8;
#pragma unroll
    for (int ks = 0; ks < 4; ++ks) kq[ks] = *(const bf16x8*)(qrow + ks * 16);
    float l_run = 0.f;
    f32x16 O0, O1;   // d-half 0 / 1, accumulated over this warp's jt-half of j
#pragma unroll
    for (int r = 0; r < 16; ++r) { O0[r] = 0.f; O1[r] = 0.f; }
    int srow = tid >> 3, sc = (tid & 7) << 3;
    const unsigned short* kgb = KB + (size_t)bh * LL * HD;
    const unsigned short* vgb = VTB + (size_t)bh * HD * LL;
    const unsigned short* bxg = BIDX + ((size_t)b << 20) + (size_t)q0 * 1024;
    // prefetch tile 0 into registers
    bf16x8 kvr[2], vvr[2], bxr[2];
#pragma unroll
    for (int rep = 0; rep < 2; ++rep) {
        int r = srow + rep * 32;
        kvr[rep] = *(const bf16x8*)(kgb + (size_t)r * HD + sc);
        vvr[rep] = *(const bf16x8*)(vgb + (size_t)r * LL + sc);
        bxr[rep] = *(const bf16x8*)(bxg + (size_t)r * 1024 + sc);
    }
    __syncthreads();                      // sb visible
    float sb0 = sb[0], sb100 = sb[100];   // saturated dp-bias constants (broadcast)
    for (int kt = 0; kt < 16; ++kt) {
        __syncthreads();
        // commit staged registers to LDS
#pragma unroll
        for (int rep = 0; rep < 2; ++rep) {
            int r = srow + rep * 32;
            *(bf16x8*)&Ks[r * STR + sc] = kvr[rep];
            *(bf16x8*)&Vt[r * STR + sc] = vvr[rep];
            *(bf16x8*)&Bxs[r * BXS + sc] = bxr[rep];
        }
        // issue prefetch for tile kt+1 (hidden under the compute phase below)
        if (kt + 1 < 16) {
#pragma unroll
            for (int rep = 0; rep < 2; ++rep) {
                int r = srow + rep * 32;
                kvr[rep] = *(const bf16x8*)(kgb + (size_t)((kt + 1) * 64 + r) * HD + sc);
                vvr[rep] = *(const bf16x8*)(vgb + (size_t)r * LL + (kt + 1) * 64 + sc);
                bxr[rep] = *(const bf16x8*)(bxg + (size_t)r * 1024 + (kt + 1) * 64 + sc);
            }
        }
        __syncthreads();
        // ---- S^T = K . Q^T  (C: col=lane&31 -> i, row=reg -> j_local) ----
        f32x16 st;
#pragma unroll
        for (int r = 0; r < 16; ++r) st[r] = 0.f;
#pragma unroll
        for (int ks = 0; ks < 4; ++ks) {
            bf16x8 ak = *(const bf16x8*)&Ks[(jt * 32 + li) * STR + ks * 16 + qd * 8];
            st = __builtin_amdgcn_mfma_f32_32x32x16_bf16(ak, kq[ks], st, 0, 0, 0);
        }
        // ---- biases: warp-uniform saturation test for the dp term ----
        int delta = (kt << 6) + (jt << 5) - q0 - (it << 5);   // j - i offset of tile
        if (delta >= 81 || delta <= -81) {
            float db = (delta >= 81) ? sb100 : sb0;
#pragma unroll
            for (int g4 = 0; g4 < 4; ++g4) {
                ushort4 bi = *(const ushort4*)&Bxs[i_loc * BXS + jt * 32 + g4 * 8 + qd * 4];
#pragma unroll
                for (int q = 0; q < 4; ++q) {
                    int r = g4 * 4 + q;
                    unsigned u = (q == 0) ? bi.x : (q == 1) ? bi.y : (q == 2) ? bi.z : bi.w;
                    st[r] = st[r] + db + sb[u >> 8];
                }
            }
        } else {
#pragma unroll
            for (int g4 = 0; g4 < 4; ++g4) {
                ushort4 bi = *(const ushort4*)&Bxs[i_loc * BXS + jt * 32 + g4 * 8 + qd * 4];
#pragma unroll
                for (int q = 0; q < 4; ++q) {
                    int r = g4 * 4 + q;
                    unsigned u = (q == 0) ? bi.x : (q == 1) ? bi.y : (q == 2) ? bi.z : bi.w;
                    st[r] = st[r] + sb[u & 0xffu] + sb[u >> 8];
                }
            }
        }
        // ---- exp2 (fixed m=0), pack pairs to bf16, accumulate l in-register ----
        float rs = 0.f;
        unsigned W[8];
#pragma unroll
        for (int pr = 0; pr < 8; ++pr) {
            float p0 = __builtin_amdgcn_exp2f(st[2 * pr]);
            float p1 = __builtin_amdgcn_exp2f(st[2 * pr + 1]);
            rs += p0 + p1;
            unsigned wpk;
            asm("v_cvt_pk_bf16_f32 %0, %1, %2" : "=v"(wpk) : "v"(p0), "v"(p1));
            W[pr] = wpk;   // low = j, high = j+1 (j_local = (2pr&3)+8*(pr>>1)+4*qd)
        }
        rs += __shfl_xor(rs, 32);
        l_run += rs;
        // ---- cross-half exchange -> A-fragments, no LDS round-trip ----
        auto s02 = __builtin_amdgcn_permlane32_swap(W[0], W[2], false, false);
        auto s13 = __builtin_amdgcn_permlane32_swap(W[1], W[3], false, false);
        auto s46 = __builtin_amdgcn_permlane32_swap(W[4], W[6], false, false);
        auto s57 = __builtin_amdgcn_permlane32_swap(W[5], W[7], false, false);
        u32x4 a0w = {(unsigned)s02[0], (unsigned)s13[0], (unsigned)s02[1], (unsigned)s13[1]};
        u32x4 a1w = {(unsigned)s46[0], (unsigned)s57[0], (unsigned)s46[1], (unsigned)s57[1]};
        bf16x8 ap0 = __builtin_bit_cast(bf16x8, a0w);   // j_local 0..15 of jt-half
        bf16x8 ap1 = __builtin_bit_cast(bf16x8, a1w);   // j_local 16..31
        // ---- PV: O[dh] += P[i][j in jt-half] * V[j][dh*32+li] ----
        {
            bf16x8 bv;
            bv = *(const bf16x8*)&Vt[(li) * STR + jt * 32 + qd * 8];
            O0 = __builtin_amdgcn_mfma_f32_32x32x16_bf16(ap0, bv, O0, 0, 0, 0);
            bv = *(const bf16x8*)&Vt[(li) * STR + jt * 32 + 16 + qd * 8];
            O0 = __builtin_amdgcn_mfma_f32_32x32x16_bf16(ap1, bv, O0, 0, 0, 0);
            bv = *(const bf16x8*)&Vt[(32 + li) * STR + jt * 32 + qd * 8];
            O1 = __builtin_amdgcn_mfma_f32_32x32x16_bf16(ap0, bv, O1, 0, 0, 0);
            bv = *(const bf16x8*)&Vt[(32 + li) * STR + jt * 32 + 16 + qd * 8];
            O1 = __builtin_amdgcn_mfma_f32_32x32x16_bf16(ap1, bv, O1, 0, 0, 0);
        }
    }
    // ---- end-of-kernel l exchange + jt-partial merge ----
    if (qd == 0) psum_s[jt * 64 + i_loc] = l_run;
    __syncthreads();   // PV reads of Vt done; psum visible
    if (jt == 0 && qd == 0)
        linv_s[i_loc] = 1.0f / (psum_s[i_loc] + psum_s[64 + i_loc]);
    if (jt == 1) {
        int ibase = it * 32;
#pragma unroll
        for (int r = 0; r < 16; ++r) {
            int irow = (r & 3) + ((r >> 2) << 3) + (qd << 2);
            fcomb[(ibase + irow) * 64 + li] = O0[r];
            fcomb[(ibase + irow) * 64 + 32 + li] = O1[r];
        }
    }
    __syncthreads();
    if (jt == 0) {
        int ibase = it * 32;
#pragma unroll
        for (int r = 0; r < 16; ++r) {
            int irow = (r & 3) + ((r >> 2) << 3) + (qd << 2);
            float inv = linv_s[ibase + irow];
            float v0 = (O0[r] + fcomb[(ibase + irow) * 64 + li]) * inv;
            float v1 = (O1[r] + fcomb[(ibase + irow) * 64 + 32 + li]) * inv;
            size_t rowoff = (size_t)(b * LL + q0 + ibase + irow) * DD + h * HD;
            aout[rowoff + li] = f2bf(v0);
            aout[rowoff + 32 + li] = f2bf(v1);
        }
    }
}

extern "C" void kernel_launch(void* const* d_in, const int* in_sizes, int n_in,
                              void* d_out, int out_size, void* d_ws, size_t ws_size,
                              hipStream_t stream) {
    const float* query    = (const float*)d_in[0];
    const float* patch    = (const float*)d_in[3];
    const float* in_w     = (const float*)d_in[4];
    const float* in_b     = (const float*)d_in[5];
    const float* out_w    = (const float*)d_in[6];
    const float* out_b    = (const float*)d_in[7];
    const float* rel_bias = (const float*)d_in[8];
    float* ws  = (float*)d_ws;
    float* out = (float*)d_out;

    unsigned short* qb   = (unsigned short*)(ws + QB_F);
    unsigned short* kb   = (unsigned short*)(ws + KB_F);
    unsigned short* vtb  = (unsigned short*)(ws + VTB_F);
    unsigned short* xbf  = (unsigned short*)(ws + XBF_F);   // query bf16, then aout bf16
    unsigned short* wibf = (unsigned short*)(ws + WIBF_F);
    unsigned short* wobf = (unsigned short*)(ws + WOBF_F);
    unsigned short* bidx = (unsigned short*)(ws + BIDX_F);

    prep_kernel<<<5380, 256, 0, stream>>>(patch, ws + DT_F, query, in_w, out_w,
                                          xbf, wibf, wobf);
    bidx_kernel<<<2048, 256, 0, stream>>>(patch, ws + DT_F, bidx);
    qkv_gemm<<<dim3(32, 18), 256, 0, stream>>>(xbf, wibf, in_b, qb, kb, vtb);
    attn_kernel<<<dim3(BB * HH, LL / 64), 256, 0, stream>>>(
        qb, kb, vtb, bidx, rel_bias, xbf);
    out_gemm<<<dim3(32, 6), 256, 0, stream>>>(xbf, wobf, out_b, out);
}

// Round 5
// 190.672 us; speedup vs baseline: 1.1386x; 1.1386x over previous
//
#include <hip/hip_runtime.h>
#include <hip/hip_bf16.h>

// Problem constants
#define BB 4
#define LL 1024
#define DD 768
#define HH 12
#define HD 64
#define MREL 50
#define NBIAS 101   // 2*MREL+1
#define GK 768      // GEMM K (= DD)
#define STR 72      // attn K/V LDS stride in ushorts (144 B, b128-aligned)
#define BXS 68      // bias-idx LDS stride in ushorts (136 B, b64-aligned, 2-way banks)

#define NEG_INF (-__builtin_inff())

// Workspace layout (float offsets into d_ws)
#define QB_F   ((size_t)0)          // q bf16 [B,H,L,64] (pre-scaled 1/8 * log2e)
#define KB_F   ((size_t)1572864)    // k bf16 [B,H,L,64]
#define VTB_F  ((size_t)3145728)    // v^T bf16 [B,H,64,L]
#define XBF_F  ((size_t)4718592)    // query bf16; later aout bf16 [B,L,768]
#define WIBF_F ((size_t)6291456)    // in_proj_w bf16 [2304,768]
#define WOBF_F ((size_t)7176192)    // out_proj_w bf16 [768,768]
#define BIDX_F ((size_t)7471104)    // packed bias idx u16 [B,L(i),L(j)] = 8 MB
#define DT_F   ((size_t)9568256)    // dt[B]
// total ~9.57M floats = 38.3 MB

#define NQ4  (BB*LL*DD)       // 3145728
#define NWI4 (3*DD*DD)        // 1769472

typedef __attribute__((ext_vector_type(8)))  short bf16x8;
typedef __attribute__((ext_vector_type(4)))  float f32x4;
typedef __attribute__((ext_vector_type(16))) float f32x16;
typedef __attribute__((ext_vector_type(4)))  unsigned int u32x4;

__device__ __forceinline__ unsigned short f2bf(float f) {
    unsigned u = __float_as_uint(f);
    u += 0x7fffu + ((u >> 16) & 1u);   // RN-even (finite inputs)
    return (unsigned short)(u >> 16);
}

// async global->LDS, 16 bytes per lane (LDS dest = wave-uniform base + lane*16)
__device__ __forceinline__ void gload_lds16(const void* g, void* l) {
    __builtin_amdgcn_global_load_lds(
        (const __attribute__((address_space(1))) void*)g,
        (__attribute__((address_space(3))) void*)l, 16, 0, 0);
}

// ---------------------------------------------------------------------------
// prep_kernel: blocks 0..3 = per-batch dt (u64 composite-key rank-count
// nanmedian); blocks 4.. = fp32->bf16 cvt of query/in_proj_w/out_proj_w.
// ---------------------------------------------------------------------------
__global__ __launch_bounds__(256) void prep_kernel(
    const float* __restrict__ patch, float* __restrict__ dt,
    const float* __restrict__ q, const float* __restrict__ wi, const float* __restrict__ wo,
    unsigned short* __restrict__ qd_, unsigned short* __restrict__ wid,
    unsigned short* __restrict__ wod) {
    int tid = threadIdx.x;
    if (blockIdx.x >= 4) {
        int i = ((blockIdx.x - 4) * 256 + tid) * 4;
        const float* src; unsigned short* dst; int off;
        if (i < NQ4)              { src = q;  dst = qd_; off = i; }
        else if (i < NQ4 + NWI4)  { src = wi; dst = wid; off = i - NQ4; }
        else                      { src = wo; dst = wod; off = i - NQ4 - NWI4; }
        float4 v = *(const float4*)&src[off];
        ushort4 o;
        o.x = f2bf(v.x); o.y = f2bf(v.y); o.z = f2bf(v.z); o.w = f2bf(v.w);
        *(ushort4*)&dst[off] = o;
        return;
    }
    // ---- dt path (blocks 0..3) ----
    __shared__ __align__(16) float del[1024];
    __shared__ __align__(16) unsigned long long key64[1024];
    __shared__ int nvalid;
    __shared__ float acc;
    int b = blockIdx.x;
    if (tid == 0) { nvalid = 0; acc = 0.f; }
    __syncthreads();
    int cnt = 0;
#pragma unroll
    for (int r = 0; r < 4; ++r) {
        int i = tid + r * 256;
        float v = __builtin_nanf("");
        if (i < LL - 1) {
            v = patch[b * LL + i + 1] - patch[b * LL + i];
            if (v == v) ++cnt;
        }
        del[i] = v;
        unsigned bits = (v == v) ? __float_as_uint(v) : 0x7FC00000u;
        unsigned ordk = (bits & 0x80000000u) ? ~bits : (bits | 0x80000000u);
        key64[i] = ((unsigned long long)ordk << 10) | (unsigned)i;
    }
    atomicAdd(&nvalid, cnt);
    __syncthreads();
    int i0 = tid, i1 = tid + 256, i2 = tid + 512, i3 = tid + 768;
    float v0 = del[i0], v1 = del[i1], v2 = del[i2], v3 = del[i3];
    unsigned long long k0 = key64[i0], k1 = key64[i1], k2 = key64[i2], k3 = key64[i3];
    int c0 = 0, c1 = 0, c2 = 0, c3 = 0;
#define CMPK(kx) { unsigned long long _k = (kx); \
    c0 += (_k < k0) ? 1 : 0; c1 += (_k < k1) ? 1 : 0; \
    c2 += (_k < k2) ? 1 : 0; c3 += (_k < k3) ? 1 : 0; }
    for (int j = 0; j < 1024; j += 8) {
        ulonglong2 a = *(const ulonglong2*)&key64[j];
        ulonglong2 bq = *(const ulonglong2*)&key64[j + 2];
        ulonglong2 cq = *(const ulonglong2*)&key64[j + 4];
        ulonglong2 dq = *(const ulonglong2*)&key64[j + 6];
        CMPK(a.x); CMPK(a.y); CMPK(bq.x); CMPK(bq.y);
        CMPK(cq.x); CMPK(cq.y); CMPK(dq.x); CMPK(dq.y);
    }
#undef CMPK
    int n = nvalid;
#define FIN(vr, cr) if (vr == vr) { \
    if (n & 1) { if (cr == n / 2) atomicAdd(&acc, vr); } \
    else { if (cr == n / 2 - 1 || cr == n / 2) atomicAdd(&acc, 0.5f * vr); } }
    FIN(v0, c0); FIN(v1, c1); FIN(v2, c2); FIN(v3, c3);
#undef FIN
    __syncthreads();
    if (tid == 0) {
        float m = acc;
        float res = (n > 0 && m == m && fabsf(m) != __builtin_inff() && m > 0.f) ? m : 1.0f;
        dt[b] = res;
    }
}

// ---------------------------------------------------------------------------
// Packed bias indices (head-independent): bidx[b][i][j] = dp | (fr<<8)
// ---------------------------------------------------------------------------
__global__ __launch_bounds__(256) void bidx_kernel(const float* __restrict__ patch,
                                                   const float* __restrict__ dtb,
                                                   unsigned short* __restrict__ bidx) {
    int flat = (blockIdx.x * 256 + threadIdx.x) * 8;   // u16 index
    int b = flat >> 20;
    int rem = flat & 1048575;
    int i = rem >> 10;          // q row (slow)
    int j0 = rem & 1023;        // k row base (fast, 8 consecutive)
    float pi = patch[b * LL + i];
    float inv_dt = 1.0f / dtb[b];
    float4 pa = *(const float4*)&patch[b * LL + j0];
    float4 pb4 = *(const float4*)&patch[b * LL + j0 + 4];
    unsigned out[4];
#define MK(pj, jofs, dst, shift) { \
    int d = (j0 + jofs) - i; d = d < -MREL ? -MREL : (d > MREL ? MREL : d); \
    float rt = pi - (pj); \
    if (!(rt == rt) || rt < -(float)MREL || rt > (float)MREL) rt = 0.f; \
    float fr = fminf(fmaxf(rintf(rt * inv_dt), -(float)MREL), (float)MREL); \
    unsigned u = (unsigned)(d + MREL) | (((unsigned)((int)fr + MREL)) << 8); \
    dst |= (u << shift); }
    unsigned t;
    t = 0; MK(pa.x, 0, t, 0); MK(pa.y, 1, t, 16); out[0] = t;
    t = 0; MK(pa.z, 2, t, 0); MK(pa.w, 3, t, 16); out[1] = t;
    t = 0; MK(pb4.x, 4, t, 0); MK(pb4.y, 5, t, 16); out[2] = t;
    t = 0; MK(pb4.z, 6, t, 0); MK(pb4.w, 7, t, 16); out[3] = t;
#undef MK
    *(uint4*)&bidx[flat] = *(uint4*)&out[0];
}

// ---------------------------------------------------------------------------
// R13 GEMM core: 64x128 tile, BK=64, DOUBLE-BUFFERED LDS (one barrier/K-iter;
// stage of tile t+1 issued AFTER the barrier so the compiler's vmcnt(0) drain
// at the NEXT barrier lands a full compute phase later), plus both-sides XOR
// swizzle (rule 21): global source col pre-swizzled by ((row&7)<<3), LDS dest
// linear, fragment reads apply the same XOR -> each consecutive 8-lane group
// of a ds_read_b128 hits 8 distinct 16B slots = all 32 banks (was 16-way).
// 4 waves, each owns 64x32 (acc[4][2]); grids: qkv 64x18=1152, out 64x6=384.
// LDS: 2 x (A 8KB + B 16KB) = 48 KB -> 3 blocks/CU.
// ---------------------------------------------------------------------------
#define STAGE_DB(boff, kc)                                                     \
    { _Pragma("unroll") for (int r = 0; r < 2; ++r)                            \
          gload_lds16(Ag + (size_t)(r * 32) * GK + (kc),                       \
                      smem_g + (boff) + r * 2048 + tid * 8);                   \
      _Pragma("unroll") for (int r = 0; r < 4; ++r)                            \
          gload_lds16(Bg + (size_t)(r * 32) * GK + (kc),                       \
                      smem_g + (boff) + 4096 + r * 2048 + tid * 8); }

#define GEMM_DB_MAIN()                                                         \
    __shared__ __align__(16) unsigned short smem_g[24576];                     \
    int tid = threadIdx.x;                                                     \
    int m0 = blockIdx.x << 6, n0 = blockIdx.y << 7;                            \
    int lane = tid & 63, w = tid >> 6;                                         \
    int srow = tid >> 3;                                                       \
    int scol = (((tid & 7) ^ (srow & 7)) << 3);  /* pre-swizzled source col */ \
    const unsigned short* Ag = Ab + (size_t)(m0 + srow) * GK + scol;           \
    const unsigned short* Bg = Wb + (size_t)(n0 + srow) * GK + scol;           \
    f32x4 acc[4][2];                                                           \
    _Pragma("unroll") for (int i = 0; i < 4; ++i)                              \
        _Pragma("unroll") for (int j = 0; j < 2; ++j)                          \
            acc[i][j] = (f32x4){0.f, 0.f, 0.f, 0.f};                           \
    int qd_ = lane >> 4, rl = lane & 15, xA = rl & 7;                          \
    int rB = w * 32 + rl;                                                      \
    STAGE_DB(0, 0);                                                            \
    int cur = 0;                                                               \
    for (int t = 0; t < GK / 64; ++t) {                                        \
        __syncthreads();   /* drains vmcnt -> buf[cur] staged; prev reads done */ \
        if (t + 1 < GK / 64) STAGE_DB((cur ^ 1) * 12288, (t + 1) * 64);        \
        int bo = cur * 12288;                                                  \
        const unsigned short* Abl = smem_g + bo;                               \
        const unsigned short* Bbl = smem_g + bo + 4096;                        \
        _Pragma("unroll") for (int ks = 0; ks < 2; ++ks) {                     \
            int cb = ((ks * 4 + qd_) ^ xA) << 3;   /* swizzled 16B slot */     \
            bf16x8 af[4], bfr[2];                                              \
            _Pragma("unroll") for (int i = 0; i < 4; ++i)                      \
                af[i] = *(const bf16x8*)&Abl[(rl + i * 16) * 64 + cb];         \
            _Pragma("unroll") for (int j = 0; j < 2; ++j)                      \
                bfr[j] = *(const bf16x8*)&Bbl[(rB + j * 16) * 64 + cb];        \
            _Pragma("unroll") for (int i = 0; i < 4; ++i)                      \
                _Pragma("unroll") for (int j = 0; j < 2; ++j)                  \
                    acc[i][j] = __builtin_amdgcn_mfma_f32_16x16x32_bf16(       \
                        af[i], bfr[j], acc[i][j], 0, 0, 0);                    \
        }                                                                      \
        cur ^= 1;                                                              \
    }                                                                          \
    int colL = lane & 15, rq = lane >> 4;

// QKV projection. Tiles are 64 rows x 128 cols (= 2 heads); blockIdx.y 0-5 = Q,
// 6-11 = K, 12-17 = V. Outputs staged in LDS (reusing smem_g) then written as
// coalesced 64-128 B runs. V staged TRANSPOSED.
__global__ __launch_bounds__(256) void qkv_gemm(
    const unsigned short* __restrict__ Ab, const unsigned short* __restrict__ Wb,
    const float* __restrict__ bias,
    unsigned short* __restrict__ qb, unsigned short* __restrict__ kb,
    unsigned short* __restrict__ vtb) {
    GEMM_DB_MAIN();
    int sec = n0 / DD;
    int hh0 = (n0 - sec * DD) >> 6;     // first of the 2 heads in this tile
    unsigned short* Ts = smem_g;
    __syncthreads();                    // all ds_reads of the K-loop done
    if (sec == 2) {
        // ---- V: transposed staging Ts[n_local 0..127][m_local 0..63] str 72 ----
#pragma unroll
        for (int j = 0; j < 2; ++j) {
            int col_t = w * 32 + j * 16 + colL;
            float bn = bias[n0 + col_t];
#pragma unroll
            for (int i = 0; i < 4; ++i) {
                ushort4 o;
                o.x = f2bf(acc[i][j][0] + bn);
                o.y = f2bf(acc[i][j][1] + bn);
                o.z = f2bf(acc[i][j][2] + bn);
                o.w = f2bf(acc[i][j][3] + bn);
                *(ushort4*)&Ts[col_t * 72 + i * 16 + rq * 4] = o;
            }
        }
        __syncthreads();
        int nl = tid >> 1, half = tid & 1;      // nl = dd-local 0..127
        int d768 = n0 + nl - 2 * DD;
        int hh = d768 >> 6, dd = d768 & 63;
        int b = m0 >> 10, l0 = (m0 & 1023) + half * 32;
        unsigned short* dst = vtb + (((size_t)b * HH + hh) * HD + dd) * LL + l0;
#pragma unroll
        for (int k = 0; k < 4; ++k)
            *(uint4*)&dst[k * 8] = *(const uint4*)&Ts[nl * 72 + half * 32 + k * 8];
    } else {
        // ---- Q/K: direct staging Ts[m_local 0..63][n_local 0..127] str 136 ----
        float scale = (sec == 0) ? 0.18033688011112042f : 1.0f;  // 0.125*log2(e)
#pragma unroll
        for (int j = 0; j < 2; ++j) {
            int col_t = w * 32 + j * 16 + colL;
            float bn = bias[n0 + col_t];
#pragma unroll
            for (int i = 0; i < 4; ++i) {
                int row_t = i * 16 + rq * 4;
#pragma unroll
                for (int r = 0; r < 4; ++r)
                    Ts[(row_t + r) * 136 + col_t] = f2bf((acc[i][j][r] + bn) * scale);
            }
        }
        __syncthreads();
        int ml = tid >> 2, q4 = tid & 3;        // ml = L-local 0..63
        int b = (m0 + ml) >> 10, l = (m0 + ml) & 1023;
        unsigned short* dst = (sec == 0 ? qb : kb)
                              + (((size_t)b * HH + hh0 + (q4 >> 1)) * LL + l) * HD
                              + (q4 & 1) * 32;
#pragma unroll
        for (int k = 0; k < 4; ++k)
            *(uint4*)&dst[k * 8] = *(const uint4*)&Ts[ml * 136 + q4 * 32 + k * 8];
    }
}

// Out projection: aout bf16 [4096,768] x W^T -> fp32 out (direct fp32 stores:
// each 16-lane quarter writes 64 B contiguous — acceptable).
__global__ __launch_bounds__(256) void out_gemm(
    const unsigned short* __restrict__ Ab, const unsigned short* __restrict__ Wb,
    const float* __restrict__ bias, float* __restrict__ C) {
    GEMM_DB_MAIN();
#pragma unroll
    for (int j = 0; j < 2; ++j) {
        int n = n0 + w * 32 + j * 16 + colL;
        float bn = bias[n];
#pragma unroll
        for (int i = 0; i < 4; ++i) {
            int rowb = m0 + i * 16 + rq * 4;
#pragma unroll
            for (int r = 0; r < 4; ++r)
                C[(size_t)(rowb + r) * DD + n] = acc[i][j][r] + bn;
        }
    }
}

// ---------------------------------------------------------------------------
// MFMA flash attention (R10 structure): in-register P via cvt_pk_bf16 +
// permlane32_swap; 2 barriers/iter; register prefetch of next tile.
// setprio stays reverted (R11: +3 us regression, lockstep structure).
// ---------------------------------------------------------------------------
__global__ __launch_bounds__(256) void attn_kernel(
    const unsigned short* __restrict__ QB, const unsigned short* __restrict__ KB,
    const unsigned short* __restrict__ VTB, const unsigned short* __restrict__ BIDX,
    const float* __restrict__ relb, unsigned short* __restrict__ aout) {
    __shared__ __align__(16) unsigned short smem[2 * 64 * STR + 64 * BXS];
    __shared__ float sb[NBIAS];
    __shared__ float psum_s[128];
    __shared__ float linv_s[64];
    unsigned short* Ks  = smem;                 // [64][STR]
    unsigned short* Vt  = smem + 64 * STR;      // [64][STR]
    unsigned short* Bxs = smem + 2 * 64 * STR;  // [64][BXS]
    float* fcomb = (float*)smem;                // 16 KB end-of-kernel combine (aliases Ks+Vt)

    int tid = threadIdx.x;
    int w = tid >> 6, lane = tid & 63, li = lane & 31, qd = lane >> 5;
    int jt = w & 1, it = w >> 1;
    int bh = blockIdx.x, b = bh / HH, h = bh - b * HH;
    int q0 = blockIdx.y << 6;
    if (tid < NBIAS) sb[tid] = relb[h * NBIAS + tid] * 1.44269504088896340736f;
    int i_loc = it * 32 + li;
    int i_abs = q0 + i_loc;
    bf16x8 kq[4];
    const unsigned short* qrow = QB + ((size_t)bh * LL + i_abs) * HD + qd * 8;
#pragma unroll
    for (int ks = 0; ks < 4; ++ks) kq[ks] = *(const bf16x8*)(qrow + ks * 16);
    float l_run = 0.f;
    f32x16 O0, O1;   // d-half 0 / 1, accumulated over this warp's jt-half of j
#pragma unroll
    for (int r = 0; r < 16; ++r) { O0[r] = 0.f; O1[r] = 0.f; }
    int srow = tid >> 3, sc = (tid & 7) << 3;
    const unsigned short* kgb = KB + (size_t)bh * LL * HD;
    const unsigned short* vgb = VTB + (size_t)bh * HD * LL;
    const unsigned short* bxg = BIDX + ((size_t)b << 20) + (size_t)q0 * 1024;
    // prefetch tile 0 into registers
    bf16x8 kvr[2], vvr[2], bxr[2];
#pragma unroll
    for (int rep = 0; rep < 2; ++rep) {
        int r = srow + rep * 32;
        kvr[rep] = *(const bf16x8*)(kgb + (size_t)r * HD + sc);
        vvr[rep] = *(const bf16x8*)(vgb + (size_t)r * LL + sc);
        bxr[rep] = *(const bf16x8*)(bxg + (size_t)r * 1024 + sc);
    }
    __syncthreads();                      // sb visible
    float sb0 = sb[0], sb100 = sb[100];   // saturated dp-bias constants (broadcast)
    for (int kt = 0; kt < 16; ++kt) {
        __syncthreads();
        // commit staged registers to LDS
#pragma unroll
        for (int rep = 0; rep < 2; ++rep) {
            int r = srow + rep * 32;
            *(bf16x8*)&Ks[r * STR + sc] = kvr[rep];
            *(bf16x8*)&Vt[r * STR + sc] = vvr[rep];
            *(bf16x8*)&Bxs[r * BXS + sc] = bxr[rep];
        }
        // issue prefetch for tile kt+1 (hidden under the compute phase below)
        if (kt + 1 < 16) {
#pragma unroll
            for (int rep = 0; rep < 2; ++rep) {
                int r = srow + rep * 32;
                kvr[rep] = *(const bf16x8*)(kgb + (size_t)((kt + 1) * 64 + r) * HD + sc);
                vvr[rep] = *(const bf16x8*)(vgb + (size_t)r * LL + (kt + 1) * 64 + sc);
                bxr[rep] = *(const bf16x8*)(bxg + (size_t)r * 1024 + (kt + 1) * 64 + sc);
            }
        }
        __syncthreads();
        // ---- S^T = K . Q^T  (C: col=lane&31 -> i, row=reg -> j_local) ----
        f32x16 st;
#pragma unroll
        for (int r = 0; r < 16; ++r) st[r] = 0.f;
#pragma unroll
        for (int ks = 0; ks < 4; ++ks) {
            bf16x8 ak = *(const bf16x8*)&Ks[(jt * 32 + li) * STR + ks * 16 + qd * 8];
            st = __builtin_amdgcn_mfma_f32_32x32x16_bf16(ak, kq[ks], st, 0, 0, 0);
        }
        // ---- biases: warp-uniform saturation test for the dp term ----
        int delta = (kt << 6) + (jt << 5) - q0 - (it << 5);   // j - i offset of tile
        if (delta >= 81 || delta <= -81) {
            float db = (delta >= 81) ? sb100 : sb0;
#pragma unroll
            for (int g4 = 0; g4 < 4; ++g4) {
                ushort4 bi = *(const ushort4*)&Bxs[i_loc * BXS + jt * 32 + g4 * 8 + qd * 4];
#pragma unroll
                for (int q = 0; q < 4; ++q) {
                    int r = g4 * 4 + q;
                    unsigned u = (q == 0) ? bi.x : (q == 1) ? bi.y : (q == 2) ? bi.z : bi.w;
                    st[r] = st[r] + db + sb[u >> 8];
                }
            }
        } else {
#pragma unroll
            for (int g4 = 0; g4 < 4; ++g4) {
                ushort4 bi = *(const ushort4*)&Bxs[i_loc * BXS + jt * 32 + g4 * 8 + qd * 4];
#pragma unroll
                for (int q = 0; q < 4; ++q) {
                    int r = g4 * 4 + q;
                    unsigned u = (q == 0) ? bi.x : (q == 1) ? bi.y : (q == 2) ? bi.z : bi.w;
                    st[r] = st[r] + sb[u & 0xffu] + sb[u >> 8];
                }
            }
        }
        // ---- exp2 (fixed m=0), pack pairs to bf16, accumulate l in-register ----
        float rs = 0.f;
        unsigned W[8];
#pragma unroll
        for (int pr = 0; pr < 8; ++pr) {
            float p0 = __builtin_amdgcn_exp2f(st[2 * pr]);
            float p1 = __builtin_amdgcn_exp2f(st[2 * pr + 1]);
            rs += p0 + p1;
            unsigned wpk;
            asm("v_cvt_pk_bf16_f32 %0, %1, %2" : "=v"(wpk) : "v"(p0), "v"(p1));
            W[pr] = wpk;   // low = j, high = j+1 (j_local = (2pr&3)+8*(pr>>1)+4*qd)
        }
        rs += __shfl_xor(rs, 32);
        l_run += rs;
        // ---- cross-half exchange -> A-fragments, no LDS round-trip ----
        auto s02 = __builtin_amdgcn_permlane32_swap(W[0], W[2], false, false);
        auto s13 = __builtin_amdgcn_permlane32_swap(W[1], W[3], false, false);
        auto s46 = __builtin_amdgcn_permlane32_swap(W[4], W[6], false, false);
        auto s57 = __builtin_amdgcn_permlane32_swap(W[5], W[7], false, false);
        u32x4 a0w = {(unsigned)s02[0], (unsigned)s13[0], (unsigned)s02[1], (unsigned)s13[1]};
        u32x4 a1w = {(unsigned)s46[0], (unsigned)s57[0], (unsigned)s46[1], (unsigned)s57[1]};
        bf16x8 ap0 = __builtin_bit_cast(bf16x8, a0w);   // j_local 0..15 of jt-half
        bf16x8 ap1 = __builtin_bit_cast(bf16x8, a1w);   // j_local 16..31
        // ---- PV: O[dh] += P[i][j in jt-half] * V[j][dh*32+li] ----
        {
            bf16x8 bv;
            bv = *(const bf16x8*)&Vt[(li) * STR + jt * 32 + qd * 8];
            O0 = __builtin_amdgcn_mfma_f32_32x32x16_bf16(ap0, bv, O0, 0, 0, 0);
            bv = *(const bf16x8*)&Vt[(li) * STR + jt * 32 + 16 + qd * 8];
            O0 = __builtin_amdgcn_mfma_f32_32x32x16_bf16(ap1, bv, O0, 0, 0, 0);
            bv = *(const bf16x8*)&Vt[(32 + li) * STR + jt * 32 + qd * 8];
            O1 = __builtin_amdgcn_mfma_f32_32x32x16_bf16(ap0, bv, O1, 0, 0, 0);
            bv = *(const bf16x8*)&Vt[(32 + li) * STR + jt * 32 + 16 + qd * 8];
            O1 = __builtin_amdgcn_mfma_f32_32x32x16_bf16(ap1, bv, O1, 0, 0, 0);
        }
    }
    // ---- end-of-kernel l exchange + jt-partial merge ----
    if (qd == 0) psum_s[jt * 64 + i_loc] = l_run;
    __syncthreads();   // PV reads of Vt done; psum visible
    if (jt == 0 && qd == 0)
        linv_s[i_loc] = 1.0f / (psum_s[i_loc] + psum_s[64 + i_loc]);
    if (jt == 1) {
        int ibase = it * 32;
#pragma unroll
        for (int r = 0; r < 16; ++r) {
            int irow = (r & 3) + ((r >> 2) << 3) + (qd << 2);
            fcomb[(ibase + irow) * 64 + li] = O0[r];
            fcomb[(ibase + irow) * 64 + 32 + li] = O1[r];
        }
    }
    __syncthreads();
    if (jt == 0) {
        int ibase = it * 32;
#pragma unroll
        for (int r = 0; r < 16; ++r) {
            int irow = (r & 3) + ((r >> 2) << 3) + (qd << 2);
            float inv = linv_s[ibase + irow];
            float v0 = (O0[r] + fcomb[(ibase + irow) * 64 + li]) * inv;
            float v1 = (O1[r] + fcomb[(ibase + irow) * 64 + 32 + li]) * inv;
            size_t rowoff = (size_t)(b * LL + q0 + ibase + irow) * DD + h * HD;
            aout[rowoff + li] = f2bf(v0);
            aout[rowoff + 32 + li] = f2bf(v1);
        }
    }
}

extern "C" void kernel_launch(void* const* d_in, const int* in_sizes, int n_in,
                              void* d_out, int out_size, void* d_ws, size_t ws_size,
                              hipStream_t stream) {
    const float* query    = (const float*)d_in[0];
    const float* patch    = (const float*)d_in[3];
    const float* in_w     = (const float*)d_in[4];
    const float* in_b     = (const float*)d_in[5];
    const float* out_w    = (const float*)d_in[6];
    const float* out_b    = (const float*)d_in[7];
    const float* rel_bias = (const float*)d_in[8];
    float* ws  = (float*)d_ws;
    float* out = (float*)d_out;

    unsigned short* qb   = (unsigned short*)(ws + QB_F);
    unsigned short* kb   = (unsigned short*)(ws + KB_F);
    unsigned short* vtb  = (unsigned short*)(ws + VTB_F);
    unsigned short* xbf  = (unsigned short*)(ws + XBF_F);   // query bf16, then aout bf16
    unsigned short* wibf = (unsigned short*)(ws + WIBF_F);
    unsigned short* wobf = (unsigned short*)(ws + WOBF_F);
    unsigned short* bidx = (unsigned short*)(ws + BIDX_F);

    prep_kernel<<<5380, 256, 0, stream>>>(patch, ws + DT_F, query, in_w, out_w,
                                          xbf, wibf, wobf);
    bidx_kernel<<<2048, 256, 0, stream>>>(patch, ws + DT_F, bidx);
    qkv_gemm<<<dim3(64, 18), 256, 0, stream>>>(xbf, wibf, in_b, qb, kb, vtb);
    attn_kernel<<<dim3(BB * HH, LL / 64), 256, 0, stream>>>(
        qb, kb, vtb, bidx, rel_bias, xbf);
    out_gemm<<<dim3(64, 6), 256, 0, stream>>>(xbf, wobf, out_b, out);
}